// Round 12
// baseline (2742.896 us; speedup 1.0000x reference)
//
#include <hip/hip_runtime.h>

#define HH 128
#define TT 1024
#define NFUT 64
#define MB 2
#define NBLK 256
#define NITER (TT + NFUT)  // k=0..1087; iter k computes h1(k), h2(k-1)

typedef _Float16 half8 __attribute__((ext_vector_type(8)));
typedef float floatx4 __attribute__((ext_vector_type(4)));

#define MFMA16(a, b, c) __builtin_amdgcn_mfma_f32_16x16x32_f16((a), (b), (c), 0, 0, 0)
#define SFENCE() __builtin_amdgcn_sched_barrier(0)

__device__ __forceinline__ float sigm(float v) {
  return __builtin_amdgcn_rcpf(1.0f + __builtin_amdgcn_exp2f(v * -1.442695040888963f));
}
__device__ __forceinline__ float tanh_f(float v) {
  float a = __builtin_fabsf(v);
  float e = __builtin_amdgcn_exp2f(a * -2.885390081777927f);
  float r = (1.0f - e) * __builtin_amdgcn_rcpf(1.0f + e);
  return __builtin_copysignf(r, v);
}
__device__ __forceinline__ half8 ldw8(const float* __restrict__ p) {
  half8 r;
#pragma unroll
  for (int i = 0; i < 8; ++i) r[i] = (_Float16)p[i];
  return r;
}

// Persistent pipelined 2-layer LSTM, 256 WG x 1024 thr (16 waves), MB=2 rows.
// GATE-PAIR SPLIT (r9-r11 lesson): the compiler's regalloc never budgets more
// than ~256 total regs/wave (VGPR_Count=128 arch + ~128 acc, every round) and
// at 48 weight frags (192 regs) it spills the WEIGHTS wholesale (WRITE_SIZE
// 93MB = 725B/thr = the 48x16B frag set). Fix by halving per-wave weights:
//   waves 0-7  (gp=0): gates {i,f} of their 16 units, both cells
//   waves 8-15 (gp=1): gates {g,o}; hold c1/c2 state and finalize
// 24 frags = 96 regs/wave + ~45 working < budget -> resident.
// IF waves pass sigm(i),sigm(f) to GO waves via sif[] LDS.
// Iter k computes h1(k) and h2(k-1) (pipelined); all MFMA A-operands are
// prev-iter buffers. Encoder: 2 barriers/iter; future (64 iters): 4 barriers
// (opart -> x feedback -> cell1 sif -> cell1 finalize).
// Race audit: sif[1] w@win1(IF) B1 r@win2(GO); sif[0] enc w@win1 r@win2,
// fut w@win3 r@win4; h2b[cur] w@win2 B r@win1(k+1); h1b[cur] w@win2/win4
// B r@win1(k+1); opart w@win2 B2 r@win3, next w after B4+B1.
__global__
__attribute__((amdgpu_flat_work_group_size(1024, 1024), amdgpu_waves_per_eu(4, 4)))
void lstm_kernel(
    const float* __restrict__ x,
    const float* __restrict__ W_ih1, const float* __restrict__ b_ih1,
    const float* __restrict__ W_hh1, const float* __restrict__ b_hh1,
    const float* __restrict__ W_ih2, const float* __restrict__ b_ih2,
    const float* __restrict__ W_hh2, const float* __restrict__ b_hh2,
    const float* __restrict__ W_out, const float* __restrict__ b_out,
    float* __restrict__ out)
{
  __shared__ __align__(16) _Float16 h1b[2][2048];  // A-frag order; rows>=MB stay 0
  __shared__ __align__(16) _Float16 h2b[2][2048];
  __shared__ float xs[TT * MB];                    // [t][b] f32
  __shared__ float sif[2][2][2][128];              // [cell][gate i/f][row][unit]
  __shared__ float opart[8 * MB];

  const int tid = (int)threadIdx.x;
  const int lane = tid & 63;
  const int w = tid >> 6;
  const int gp = w >> 3;           // 0: gates {i,f}; 1: gates {g,o}
  const int nw = w & 7;            // unit block
  const int jl = lane & 15;
  const int rg = lane >> 4;
  const int j = nw * 16 + jl;
  const int q0 = gp * 2, q1 = gp * 2 + 1;  // torch gate order i,f,g,o
  const int b0g = (int)blockIdx.x * MB;

  for (int idx = tid; idx < TT * MB; idx += 1024) {
    int t = idx & (TT - 1);
    int bb = idx >> 10;
    xs[t * MB + bb] = x[(b0g + bb) * TT + t];
  }
  for (int idx = tid; idx < 2 * 2048; idx += 1024) {
    h1b[idx >> 11][idx & 2047] = (_Float16)0.0f;
    h2b[idx >> 11][idx & 2047] = (_Float16)0.0f;
  }

  // ---- 24 named weight B-fragments per wave (A=W_hh1, H=W_hh2, I=W_ih2) ----
  half8 Aa0, Aa1, Aa2, Aa3, Ab0, Ab1, Ab2, Ab3;
  half8 Ha0, Ha1, Ha2, Ha3, Hb0, Hb1, Hb2, Hb3;
  half8 Ia0, Ia1, Ia2, Ia3, Ib0, Ib1, Ib2, Ib3;
#define LDW(N, Q, P) do { \
    const float* _p = (P) + ((Q) * HH + j) * HH + rg * 8; \
    N##0 = ldw8(_p);      N##1 = ldw8(_p + 32); \
    N##2 = ldw8(_p + 64); N##3 = ldw8(_p + 96); } while (0)
  LDW(Aa, q0, W_hh1); LDW(Ab, q1, W_hh1);
  LDW(Ha, q0, W_hh2); LDW(Hb, q1, W_hh2);
  LDW(Ia, q0, W_ih2); LDW(Ib, q1, W_ih2);

  const float b1a = b_ih1[q0 * HH + j] + b_hh1[q0 * HH + j];
  const float b1b = b_ih1[q1 * HH + j] + b_hh1[q1 * HH + j];
  const float b2a = b_ih2[q0 * HH + j] + b_hh2[q0 * HH + j];
  const float b2b = b_ih2[q1 * HH + j] + b_hh2[q1 * HH + j];
  const float w1a = W_ih1[q0 * HH + j];
  const float w1b = W_ih1[q1 * HH + j];
  const float wo = W_out[j];
  const float bo = b_out[0];
  float c1a = 0.f, c1b = 0.f, c2a = 0.f, c2b = 0.f;  // GO waves, lanes 0-15

  __syncthreads();

  const int aoff = lane * 8;
  const int wb = ((j >> 5) << 9) + (((j >> 3) & 3) << 7) + (j & 7);

#define C2K(KF) do { \
    half8 bv = *(const half8*)(&h2b[prv][KF * 512 + aoff]); \
    p0 = MFMA16(bv, Ha##KF, p0); p1 = MFMA16(bv, Hb##KF, p1); \
    half8 aw = *(const half8*)(&h1b[prv][KF * 512 + aoff]); \
    p0 = MFMA16(aw, Ia##KF, p0); p1 = MFMA16(aw, Ib##KF, p1); } while (0)
#define C1K(KF) do { \
    half8 av = *(const half8*)(&h1b[prv][KF * 512 + aoff]); \
    p0 = MFMA16(av, Aa##KF, p0); p1 = MFMA16(av, Ab##KF, p1); } while (0)

  for (int k = 0; k < NITER; ++k) {
    const int cur = k & 1;
    const int prv = cur ^ 1;
    const bool fut = (k >= TT);
    const bool doC1 = (k <= NITER - 2);

    // ---- win1: all MFMA (cell2 pair then cell1 pair), extract to scalars ----
    floatx4 p0 = {0.f,0.f,0.f,0.f}, p1 = {0.f,0.f,0.f,0.f};
    __builtin_amdgcn_s_setprio(1);
    C2K(0); C2K(1); C2K(2); C2K(3);
    __builtin_amdgcn_s_setprio(0);
    SFENCE();
    float e20 = p0[0], e21 = p0[1], f20 = p1[0], f21 = p1[1];
    SFENCE();
    p0 = (floatx4){0.f,0.f,0.f,0.f}; p1 = (floatx4){0.f,0.f,0.f,0.f};
    __builtin_amdgcn_s_setprio(1);
    C1K(0); C1K(1); C1K(2); C1K(3);
    __builtin_amdgcn_s_setprio(0);
    SFENCE();
    float e10 = p0[0], e11 = p0[1], f10 = p1[0], f11 = p1[1];

    float x0 = 0.f, x1 = 0.f;
    if (!fut) { x0 = xs[k * MB + 0]; x1 = xs[k * MB + 1]; }

    if (gp == 0 && lane < 16) {
      // IF waves: publish sigm(i), sigm(f). cell2 always; cell1 if encoder.
      sif[1][0][0][j] = sigm(e20 + b2a);
      sif[1][0][1][j] = sigm(e21 + b2a);
      sif[1][1][0][j] = sigm(f20 + b2b);
      sif[1][1][1][j] = sigm(f21 + b2b);
      if (!fut) {
        sif[0][0][0][j] = sigm(e10 + x0 * w1a + b1a);
        sif[0][0][1][j] = sigm(e11 + x1 * w1a + b1a);
        sif[0][1][0][j] = sigm(f10 + x0 * w1b + b1b);
        sif[0][1][1][j] = sigm(f11 + x1 * w1b + b1b);
      }
    }
    __syncthreads();  // B1: sif (and, encoder, cell1 sif) published

    // ---- win2: GO waves finalize cell2 -> h2(k-1) (+ projection if fut) ----
    if (gp == 1 && k >= 1) {
      float si0 = sif[1][0][0][j], si1 = sif[1][0][1][j];
      float sf0 = sif[1][1][0][j], sf1 = sif[1][1][1][j];
      c2a = sf0 * c2a + si0 * tanh_f(e20 + b2a);   // e2x = gate g raw
      c2b = sf1 * c2b + si1 * tanh_f(e21 + b2a);
      float h20 = sigm(f20 + b2b) * tanh_f(c2a);   // f2x = gate o raw
      float h21 = sigm(f21 + b2b) * tanh_f(c2b);
      if (lane < 16) {
        h2b[cur][wb] = (_Float16)h20;
        h2b[cur][wb + 8] = (_Float16)h21;
      }
      if (fut) {
        float u0 = h20 * wo, u1 = h21 * wo;
        u0 += __shfl_xor(u0, 1); u1 += __shfl_xor(u1, 1);
        u0 += __shfl_xor(u0, 2); u1 += __shfl_xor(u1, 2);
        u0 += __shfl_xor(u0, 4); u1 += __shfl_xor(u1, 4);
        u0 += __shfl_xor(u0, 8); u1 += __shfl_xor(u1, 8);
        if (lane == 0) {
          opart[nw * MB + 0] = u0;
          opart[nw * MB + 1] = u1;
        }
      }
    }

    if (!fut) {
      // encoder: GO also finalizes cell1 -> h1(k) in win2
      if (gp == 1) {
        float si0 = sif[0][0][0][j], si1 = sif[0][0][1][j];
        float sf0 = sif[0][1][0][j], sf1 = sif[0][1][1][j];
        c1a = sf0 * c1a + si0 * tanh_f(e10 + x0 * w1a + b1a);
        c1b = sf1 * c1b + si1 * tanh_f(e11 + x1 * w1a + b1a);
        float h10 = sigm(f10 + x0 * w1b + b1b) * tanh_f(c1a);
        float h11 = sigm(f11 + x1 * w1b + b1b) * tanh_f(c1b);
        if (lane < 16) {
          h1b[cur][wb] = (_Float16)h10;
          h1b[cur][wb + 8] = (_Float16)h11;
        }
      }
      __syncthreads();  // B2 (end of encoder iter)
    } else {
      __syncthreads();  // B2: opart published
      // win3: everyone computes x(k) = out(k-1); w0 writes out; IF cell1 sif
      float s0 = bo, s1 = bo;
#pragma unroll
      for (int p = 0; p < 8; ++p) {
        s0 += opart[p * MB + 0];
        s1 += opart[p * MB + 1];
      }
      x0 = s0; x1 = s1;
      if (w == 0 && lane < MB) out[(b0g + lane) * NFUT + (k - TT)] = (lane == 0) ? s0 : s1;
      if (gp == 0 && lane < 16 && doC1) {
        sif[0][0][0][j] = sigm(e10 + x0 * w1a + b1a);
        sif[0][0][1][j] = sigm(e11 + x1 * w1a + b1a);
        sif[0][1][0][j] = sigm(f10 + x0 * w1b + b1b);
        sif[0][1][1][j] = sigm(f11 + x1 * w1b + b1b);
      }
      __syncthreads();  // B3: cell1 sif published
      // win4: GO finalizes cell1 -> h1(k)
      if (gp == 1 && doC1) {
        float si0 = sif[0][0][0][j], si1 = sif[0][0][1][j];
        float sf0 = sif[0][1][0][j], sf1 = sif[0][1][1][j];
        c1a = sf0 * c1a + si0 * tanh_f(e10 + x0 * w1a + b1a);
        c1b = sf1 * c1b + si1 * tanh_f(e11 + x1 * w1a + b1a);
        float h10 = sigm(f10 + x0 * w1b + b1b) * tanh_f(c1a);
        float h11 = sigm(f11 + x1 * w1b + b1b) * tanh_f(c1b);
        if (lane < 16) {
          h1b[cur][wb] = (_Float16)h10;
          h1b[cur][wb + 8] = (_Float16)h11;
        }
      }
      __syncthreads();  // B4 (end of future iter)
    }
    SFENCE();
  }
}

extern "C" void kernel_launch(void* const* d_in, const int* in_sizes, int n_in,
                              void* d_out, int out_size, void* d_ws, size_t ws_size,
                              hipStream_t stream) {
  const float* x     = (const float*)d_in[0];
  const float* W_ih1 = (const float*)d_in[1];
  const float* b_ih1 = (const float*)d_in[2];
  const float* W_hh1 = (const float*)d_in[3];
  const float* b_hh1 = (const float*)d_in[4];
  const float* W_ih2 = (const float*)d_in[5];
  const float* b_ih2 = (const float*)d_in[6];
  const float* W_hh2 = (const float*)d_in[7];
  const float* b_hh2 = (const float*)d_in[8];
  const float* W_out = (const float*)d_in[9];
  const float* b_out = (const float*)d_in[10];
  (void)in_sizes; (void)n_in; (void)out_size; (void)d_ws; (void)ws_size;

  lstm_kernel<<<dim3(NBLK), dim3(1024), 0, stream>>>(
      x, W_ih1, b_ih1, W_hh1, b_hh1, W_ih2, b_ih2, W_hh2, b_hh2, W_out, b_out,
      (float*)d_out);
}

// Round 13
// 2527.645 us; speedup vs baseline: 1.0852x; 1.0852x over previous
//
#include <hip/hip_runtime.h>

#define HH 128
#define TT 1024
#define NFUT 64
#define MB 2
#define NBLK 256
#define NITER (TT + NFUT)  // k=0..1087; iter k computes h1(k), h2(k-1)

typedef _Float16 half8 __attribute__((ext_vector_type(8)));
typedef float floatx4 __attribute__((ext_vector_type(4)));

#define MFMA16(a, b, c) __builtin_amdgcn_mfma_f32_16x16x32_f16((a), (b), (c), 0, 0, 0)

__device__ __forceinline__ float sigm(float v) {
  return __builtin_amdgcn_rcpf(1.0f + __builtin_amdgcn_exp2f(v * -1.442695040888963f));
}
__device__ __forceinline__ float tanh_f(float v) {
  float a = __builtin_fabsf(v);
  float e = __builtin_amdgcn_exp2f(a * -2.885390081777927f);
  float r = (1.0f - e) * __builtin_amdgcn_rcpf(1.0f + e);
  return __builtin_copysignf(r, v);
}
__device__ __forceinline__ half8 ldw8(const float* __restrict__ p) {
  half8 r;
#pragma unroll
  for (int i = 0; i < 8; ++i) r[i] = (_Float16)p[i];
  return r;
}

// Persistent pipelined 2-layer LSTM, 256 WG x 256 thr (4 waves), MB=2 rows/WG.
//
// REGISTER LAW (r1-r12): allocator budget = 512-reg SIMD pool / waves-per-SIMD
// (observed VGPR_Count: 2 waves/SIMD -> 128 arch (+128 acc = 256 total);
// 4 waves/SIMD -> 64). The 192-reg weight set + ~60 working NEVER fits 256 ->
// every fused structure spilled the weights (26-95 MB WRITE_SIZE).
// FIX: 1 wave/SIMD (256-thr WG, waves_per_eu(1,1)) -> 512 regs/wave budget.
// Each wave owns 32 units (2 N-tiles) of BOTH cells: 96 B-frags = 384 regs
// + ~95 working ~= 480 < 512. Weights resident, 8 independent acc chains
// saturate the SIMD's XDL from one wave; compiler free to interleave VALU
// into the MFMA shadow (no SFENCE, no setprio - nothing to arbitrate).
//
// Dataflow = r9-r11 (passed 3x): iter k computes h1(k) and h2(k-1); all MFMA
// A-operands are prev-iter buffers -> ONE barrier/iter (encoder); future
// iters add a mid-barrier for the out->x feedback.
// Accs zero-init (AGPR-friendly); bias/x added post-MFMA (r8 lesson).
__global__
__attribute__((amdgpu_flat_work_group_size(256, 256), amdgpu_waves_per_eu(1, 1)))
void lstm_kernel(
    const float* __restrict__ x,
    const float* __restrict__ W_ih1, const float* __restrict__ b_ih1,
    const float* __restrict__ W_hh1, const float* __restrict__ b_hh1,
    const float* __restrict__ W_ih2, const float* __restrict__ b_ih2,
    const float* __restrict__ W_hh2, const float* __restrict__ b_hh2,
    const float* __restrict__ W_out, const float* __restrict__ b_out,
    float* __restrict__ out)
{
  __shared__ __align__(16) _Float16 h1b[2][2048];  // A-frag order; rows>=MB stay 0
  __shared__ __align__(16) _Float16 h2b[2][2048];
  __shared__ float xs[TT * MB];                    // [t][b] f32
  __shared__ float opart[4 * MB];

  const int tid = (int)threadIdx.x;
  const int lane = tid & 63;
  const int w = tid >> 6;          // wave 0..3, owns units [32w, 32w+32)
  const int jl = lane & 15;
  const int rg = lane >> 4;
  const int b0g = (int)blockIdx.x * MB;

  for (int idx = tid; idx < TT * MB; idx += 256) {
    int t = idx & (TT - 1);
    int bb = idx >> 10;
    xs[t * MB + bb] = x[(b0g + bb) * TT + t];
  }
  for (int idx = tid; idx < 2 * 2048; idx += 256) {
    h1b[idx >> 11][idx & 2047] = (_Float16)0.0f;
    h2b[idx >> 11][idx & 2047] = (_Float16)0.0f;
  }

  // ---- 96 named weight B-fragments. Slot s = gate*2 + tile (tile: 16-unit
  // half of this wave's 32 units). A=W_hh1, H=W_hh2, I=W_ih2; kf=0..3.
  half8 A00,A01,A02,A03, A10,A11,A12,A13, A20,A21,A22,A23, A30,A31,A32,A33,
        A40,A41,A42,A43, A50,A51,A52,A53, A60,A61,A62,A63, A70,A71,A72,A73;
  half8 H00,H01,H02,H03, H10,H11,H12,H13, H20,H21,H22,H23, H30,H31,H32,H33,
        H40,H41,H42,H43, H50,H51,H52,H53, H60,H61,H62,H63, H70,H71,H72,H73;
  half8 I00,I01,I02,I03, I10,I11,I12,I13, I20,I21,I22,I23, I30,I31,I32,I33,
        I40,I41,I42,I43, I50,I51,I52,I53, I60,I61,I62,I63, I70,I71,I72,I73;
#define LDWS(N, S, Q, T, P) do { \
    const float* _p = (P) + ((Q) * HH + (w * 32 + (T) * 16 + jl)) * HH + rg * 8; \
    N##S##0 = ldw8(_p);      N##S##1 = ldw8(_p + 32); \
    N##S##2 = ldw8(_p + 64); N##S##3 = ldw8(_p + 96); } while (0)
  LDWS(A,0,0,0,W_hh1); LDWS(A,1,0,1,W_hh1); LDWS(A,2,1,0,W_hh1); LDWS(A,3,1,1,W_hh1);
  LDWS(A,4,2,0,W_hh1); LDWS(A,5,2,1,W_hh1); LDWS(A,6,3,0,W_hh1); LDWS(A,7,3,1,W_hh1);
  LDWS(H,0,0,0,W_hh2); LDWS(H,1,0,1,W_hh2); LDWS(H,2,1,0,W_hh2); LDWS(H,3,1,1,W_hh2);
  LDWS(H,4,2,0,W_hh2); LDWS(H,5,2,1,W_hh2); LDWS(H,6,3,0,W_hh2); LDWS(H,7,3,1,W_hh2);
  LDWS(I,0,0,0,W_ih2); LDWS(I,1,0,1,W_ih2); LDWS(I,2,1,0,W_ih2); LDWS(I,3,1,1,W_ih2);
  LDWS(I,4,2,0,W_ih2); LDWS(I,5,2,1,W_ih2); LDWS(I,6,3,0,W_ih2); LDWS(I,7,3,1,W_ih2);

  float b1[8], b2[8], w1[8];
#pragma unroll
  for (int q = 0; q < 4; ++q) {
#pragma unroll
    for (int t = 0; t < 2; ++t) {
      int s = q * 2 + t;
      int jt = w * 32 + t * 16 + jl;
      b1[s] = b_ih1[q * HH + jt] + b_hh1[q * HH + jt];
      b2[s] = b_ih2[q * HH + jt] + b_hh2[q * HH + jt];
      w1[s] = W_ih1[q * HH + jt];
    }
  }
  const float wo0 = W_out[w * 32 + jl];
  const float wo1 = W_out[w * 32 + 16 + jl];
  const float bo = b_out[0];
  // cell states: c{cell}_{tile}{row}, lanes 0-15 meaningful
  float c1_00 = 0.f, c1_01 = 0.f, c1_10 = 0.f, c1_11 = 0.f;
  float c2_00 = 0.f, c2_01 = 0.f, c2_10 = 0.f, c2_11 = 0.f;

  __syncthreads();

  const int aoff = lane * 8;
  const int j0 = w * 32 + jl, j1 = j0 + 16;
  const int wb0 = ((j0 >> 5) << 9) + (((j0 >> 3) & 3) << 7) + (j0 & 7);
  const int wb1 = ((j1 >> 5) << 9) + (((j1 >> 3) & 3) << 7) + (j1 & 7);

#define C2K(K) do { \
    half8 bv = *(const half8*)(&h2b[prv][K * 512 + aoff]); \
    p0 = MFMA16(bv, H0##K, p0); p1 = MFMA16(bv, H1##K, p1); \
    p2 = MFMA16(bv, H2##K, p2); p3 = MFMA16(bv, H3##K, p3); \
    p4 = MFMA16(bv, H4##K, p4); p5 = MFMA16(bv, H5##K, p5); \
    p6 = MFMA16(bv, H6##K, p6); p7 = MFMA16(bv, H7##K, p7); \
    half8 aw = *(const half8*)(&h1b[prv][K * 512 + aoff]); \
    p0 = MFMA16(aw, I0##K, p0); p1 = MFMA16(aw, I1##K, p1); \
    p2 = MFMA16(aw, I2##K, p2); p3 = MFMA16(aw, I3##K, p3); \
    p4 = MFMA16(aw, I4##K, p4); p5 = MFMA16(aw, I5##K, p5); \
    p6 = MFMA16(aw, I6##K, p6); p7 = MFMA16(aw, I7##K, p7); } while (0)
#define C1K(K) do { \
    half8 av = *(const half8*)(&h1b[prv][K * 512 + aoff]); \
    p0 = MFMA16(av, A0##K, p0); p1 = MFMA16(av, A1##K, p1); \
    p2 = MFMA16(av, A2##K, p2); p3 = MFMA16(av, A3##K, p3); \
    p4 = MFMA16(av, A4##K, p4); p5 = MFMA16(av, A5##K, p5); \
    p6 = MFMA16(av, A6##K, p6); p7 = MFMA16(av, A7##K, p7); } while (0)

  for (int k = 0; k < NITER; ++k) {
    const int cur = k & 1;
    const int prv = cur ^ 1;
    const bool fut = (k >= TT);
    const bool doC1 = (k <= NITER - 2);

    // ---- cell2 burst: gates2(k-1) = h2(k-2)@W_hh2^T + h1(k-1)@W_ih2^T ----
    floatx4 p0 = {0.f,0.f,0.f,0.f}, p1 = {0.f,0.f,0.f,0.f};
    floatx4 p2 = {0.f,0.f,0.f,0.f}, p3 = {0.f,0.f,0.f,0.f};
    floatx4 p4 = {0.f,0.f,0.f,0.f}, p5 = {0.f,0.f,0.f,0.f};
    floatx4 p6 = {0.f,0.f,0.f,0.f}, p7 = {0.f,0.f,0.f,0.f};
    C2K(0); C2K(1); C2K(2); C2K(3);

    // ---- finalize cell2 -> h2(k-1). Lanes 0-15 hold rows 0,1 in [0],[1].
    // slot: i={p0,p1}, f={p2,p3}, g={p4,p5}, o={p6,p7} (tile0,tile1)
    if (k >= 1) {
      float h2_00, h2_01, h2_10, h2_11;
      {
        float gi = p0[0] + b2[0], gf = p2[0] + b2[2], gg = p4[0] + b2[4], go = p6[0] + b2[6];
        c2_00 = sigm(gf) * c2_00 + sigm(gi) * tanh_f(gg);
        h2_00 = sigm(go) * tanh_f(c2_00);
        gi = p0[1] + b2[0]; gf = p2[1] + b2[2]; gg = p4[1] + b2[4]; go = p6[1] + b2[6];
        c2_01 = sigm(gf) * c2_01 + sigm(gi) * tanh_f(gg);
        h2_01 = sigm(go) * tanh_f(c2_01);
        gi = p1[0] + b2[1]; gf = p3[0] + b2[3]; gg = p5[0] + b2[5]; go = p7[0] + b2[7];
        c2_10 = sigm(gf) * c2_10 + sigm(gi) * tanh_f(gg);
        h2_10 = sigm(go) * tanh_f(c2_10);
        gi = p1[1] + b2[1]; gf = p3[1] + b2[3]; gg = p5[1] + b2[5]; go = p7[1] + b2[7];
        c2_11 = sigm(gf) * c2_11 + sigm(gi) * tanh_f(gg);
        h2_11 = sigm(go) * tanh_f(c2_11);
      }
      if (lane < 16) {
        h2b[cur][wb0] = (_Float16)h2_00;
        h2b[cur][wb0 + 8] = (_Float16)h2_01;
        h2b[cur][wb1] = (_Float16)h2_10;
        h2b[cur][wb1 + 8] = (_Float16)h2_11;
      }
      if (fut) {
        float u0 = h2_00 * wo0 + h2_10 * wo1;
        float u1 = h2_01 * wo0 + h2_11 * wo1;
        u0 += __shfl_xor(u0, 1); u1 += __shfl_xor(u1, 1);
        u0 += __shfl_xor(u0, 2); u1 += __shfl_xor(u1, 2);
        u0 += __shfl_xor(u0, 4); u1 += __shfl_xor(u1, 4);
        u0 += __shfl_xor(u0, 8); u1 += __shfl_xor(u1, 8);
        if (lane == 0) {
          opart[w * MB + 0] = u0;
          opart[w * MB + 1] = u1;
        }
      }
    }

    // ---- cell1 burst: gates1(k) = h1(k-1)@W_hh1^T ----
    p0 = (floatx4){0.f,0.f,0.f,0.f}; p1 = (floatx4){0.f,0.f,0.f,0.f};
    p2 = (floatx4){0.f,0.f,0.f,0.f}; p3 = (floatx4){0.f,0.f,0.f,0.f};
    p4 = (floatx4){0.f,0.f,0.f,0.f}; p5 = (floatx4){0.f,0.f,0.f,0.f};
    p6 = (floatx4){0.f,0.f,0.f,0.f}; p7 = (floatx4){0.f,0.f,0.f,0.f};
    C1K(0); C1K(1); C1K(2); C1K(3);

    // ---- x for step k ----
    float x0, x1;
    if (!fut) {
      x0 = xs[k * MB + 0];
      x1 = xs[k * MB + 1];
    } else {
      __syncthreads();  // publish opart: out(k-1) feedback
      float s0 = bo, s1 = bo;
#pragma unroll
      for (int p = 0; p < 4; ++p) {
        s0 += opart[p * MB + 0];
        s1 += opart[p * MB + 1];
      }
      x0 = s0; x1 = s1;
      if (w == 0 && lane < MB) out[(b0g + lane) * NFUT + (k - TT)] = (lane == 0) ? s0 : s1;
    }

    // ---- finalize cell1 -> h1(k) ----
    if (doC1) {
      float h1_00, h1_01, h1_10, h1_11;
      {
        float gi = p0[0] + x0 * w1[0] + b1[0], gf = p2[0] + x0 * w1[2] + b1[2];
        float gg = p4[0] + x0 * w1[4] + b1[4], go = p6[0] + x0 * w1[6] + b1[6];
        c1_00 = sigm(gf) * c1_00 + sigm(gi) * tanh_f(gg);
        h1_00 = sigm(go) * tanh_f(c1_00);
        gi = p0[1] + x1 * w1[0] + b1[0]; gf = p2[1] + x1 * w1[2] + b1[2];
        gg = p4[1] + x1 * w1[4] + b1[4]; go = p6[1] + x1 * w1[6] + b1[6];
        c1_01 = sigm(gf) * c1_01 + sigm(gi) * tanh_f(gg);
        h1_01 = sigm(go) * tanh_f(c1_01);
        gi = p1[0] + x0 * w1[1] + b1[1]; gf = p3[0] + x0 * w1[3] + b1[3];
        gg = p5[0] + x0 * w1[5] + b1[5]; go = p7[0] + x0 * w1[7] + b1[7];
        c1_10 = sigm(gf) * c1_10 + sigm(gi) * tanh_f(gg);
        h1_10 = sigm(go) * tanh_f(c1_10);
        gi = p1[1] + x1 * w1[1] + b1[1]; gf = p3[1] + x1 * w1[3] + b1[3];
        gg = p5[1] + x1 * w1[5] + b1[5]; go = p7[1] + x1 * w1[7] + b1[7];
        c1_11 = sigm(gf) * c1_11 + sigm(gi) * tanh_f(gg);
        h1_11 = sigm(go) * tanh_f(c1_11);
      }
      if (lane < 16) {
        h1b[cur][wb0] = (_Float16)h1_00;
        h1b[cur][wb0 + 8] = (_Float16)h1_01;
        h1b[cur][wb1] = (_Float16)h1_10;
        h1b[cur][wb1 + 8] = (_Float16)h1_11;
      }
    }
    __syncthreads();  // the ONE barrier: publish h1(k), h2(k-1)
  }
}

extern "C" void kernel_launch(void* const* d_in, const int* in_sizes, int n_in,
                              void* d_out, int out_size, void* d_ws, size_t ws_size,
                              hipStream_t stream) {
  const float* x     = (const float*)d_in[0];
  const float* W_ih1 = (const float*)d_in[1];
  const float* b_ih1 = (const float*)d_in[2];
  const float* W_hh1 = (const float*)d_in[3];
  const float* b_hh1 = (const float*)d_in[4];
  const float* W_ih2 = (const float*)d_in[5];
  const float* b_ih2 = (const float*)d_in[6];
  const float* W_hh2 = (const float*)d_in[7];
  const float* b_hh2 = (const float*)d_in[8];
  const float* W_out = (const float*)d_in[9];
  const float* b_out = (const float*)d_in[10];
  (void)in_sizes; (void)n_in; (void)out_size; (void)d_ws; (void)ws_size;

  lstm_kernel<<<dim3(NBLK), dim3(256), 0, stream>>>(
      x, W_ih1, b_ih1, W_hh1, b_hh1, W_ih2, b_ih2, W_hh2, b_hh2, W_out, b_out,
      (float*)d_out);
}